// Round 11
// baseline (361.768 us; speedup 1.0000x reference)
//
#include <hip/hip_runtime.h>

typedef _Float16 f16;
typedef _Float16 f16x8 __attribute__((ext_vector_type(8)));
typedef _Float16 f16x4 __attribute__((ext_vector_type(4)));
typedef float f32x4 __attribute__((ext_vector_type(4)));
typedef float f32x16 __attribute__((ext_vector_type(16)));

#define LOG2E 1.44269504088896340736f
#define SOFF  36.0f   // fixed softmax offset (log2 domain); cancels exactly in sum(Pv)/sum(P)
#define CDIM 256
#define NPIX 4096

// async global->LDS 16B copy: lds dest = wave-uniform base + lane*16 (HW rule)
__device__ __forceinline__ void gl2lds16(const f16* g, const f16* l) {
    __builtin_amdgcn_global_load_lds((const __attribute__((address_space(1))) unsigned int*)g,
                                     (__attribute__((address_space(3))) unsigned int*)l, 16, 0, 0);
}

// ---------------- kernel 0: weights fp32 -> fp16 in MFMA A-frag layout ----------------
// WF[(ct*16+ks)*64 + lane][e] = W[ct*32+(lane&31)][ks*16+(lane>>5)*8+e]
__global__ void convert_w_kernel(const float* __restrict__ Wq, const float* __restrict__ Wk,
                                 const float* __restrict__ Wv,
                                 f16* __restrict__ WqF, f16* __restrict__ WkF,
                                 f16* __restrict__ WvF) {
    int t = blockIdx.x * 256 + threadIdx.x;   // 24576 threads: 3 matrices x 8192 groups
    int m = t >> 13;
    int g = t & 8191;
    int lane = g & 63;
    int ksct = g >> 6;                        // 0..127
    int ks = ksct & 15, ct = ksct >> 4;
    int o = ct * 32 + (lane & 31);
    int cin0 = ks * 16 + (lane >> 5) * 8;
    const float* W = (m == 0) ? Wq : ((m == 1) ? Wk : Wv);
    f16* WF = (m == 0) ? WqF : ((m == 1) ? WkF : WvF);
    const float scale = (m == 0) ? LOG2E : 1.0f;   // fold log2e into Wq
    const float* src = W + (size_t)o * CDIM + cin0;
    f16x8 v;
#pragma unroll
    for (int e = 0; e < 8; ++e) v[e] = (f16)(src[e] * scale);
    *(f16x8*)(WF + (size_t)g * 8) = v;
}

// ---------------- kernel 1: q/k/v projections (R9-verified, unified) -------------------
// qT: [B][N][C] fp16. kC: chunk-major [B][kc][j][8]. vW: [B][C][N] fp16.
__global__ __launch_bounds__(256, 2)
void proj_kernel(const float* __restrict__ x, const float* __restrict__ attr,
                 const f16* __restrict__ WqF, const float* __restrict__ bq,
                 const f16* __restrict__ WkF, const float* __restrict__ bk,
                 const f16* __restrict__ WvF, const float* __restrict__ bv,
                 f16* __restrict__ qT, f16* __restrict__ kC, f16* __restrict__ vW) {
    __shared__ __align__(16) f16 Xs[64 * 256];
    __shared__ __align__(16) f16 As[64 * 256];
    __shared__ __align__(16) f16 Ostage[4][1024];

    const int b  = blockIdx.x & 7;
    const int i0 = (blockIdx.x >> 3) * 64;
    const int t  = threadIdx.x;
    const int w = t >> 6, lane = t & 63, l31 = lane & 31, hi = lane >> 5;
    const int xu  = (l31 >> 1) & 15;
    const int hib = (hi ^ (l31 & 1)) * 8;

    {
        const int i  = t & 63;
        const int cb = t >> 6;
        const float* xb = x    + (size_t)b * CDIM * NPIX + i0 + i;
        const float* ab = attr + (size_t)b * CDIM * NPIX + i0 + i;
#pragma unroll 2
        for (int rep = 0; rep < 8; ++rep) {
            int chunk = cb * 8 + rep;
            const float* xs = xb + (size_t)(chunk * 8) * NPIX;
            const float* as_ = ab + (size_t)(chunk * 8) * NPIX;
            f16x8 xv, av;
#pragma unroll
            for (int e = 0; e < 8; ++e) {
                xv[e] = (f16)xs[(size_t)e * NPIX];
                av[e] = (f16)as_[(size_t)e * NPIX];
            }
            int phys = chunk ^ (i & 31);
            *(f16x8*)(Xs + i * 256 + phys * 8) = xv;
            *(f16x8*)(As + i * 256 + phys * 8) = av;
        }
    }
    __syncthreads();

#pragma unroll 1
    for (int k = 0; k < 12; ++k) {
        const int tt = w + 4 * k;
        const int kind = tt >> 4;          // 0=Q 1=K 2=V
        const int rr = tt & 15;
        const int ct = rr >> 1;
        const int half = rr & 1;

        const f16* WF = (kind == 0) ? WqF : ((kind == 1) ? WkF : WvF);
        const f16* Bs = (kind == 0) ? Xs : As;
        const float* bias = (kind == 0) ? bq : ((kind == 1) ? bk : bv);
        const float bscale = (kind == 0) ? LOG2E : 1.0f;

        const f16* ap = WF + (size_t)(ct * 16) * 512 + (size_t)lane * 8;
        const f16* bp = Bs + (half * 32 + l31) * 256 + hib;

        f32x16 ae, ao;
#pragma unroll
        for (int r = 0; r < 16; ++r) { ae[r] = 0.0f; ao[r] = 0.0f; }
#pragma unroll
        for (int h2 = 0; h2 < 8; ++h2) {
            f16x8 a0 = *(const f16x8*)(ap + (2 * h2) * 512);
            f16x8 a1 = *(const f16x8*)(ap + (2 * h2 + 1) * 512);
            f16x8 b0 = *(const f16x8*)(bp + (((2 * h2) ^ xu)) * 16);
            f16x8 b1 = *(const f16x8*)(bp + (((2 * h2 + 1) ^ xu)) * 16);
            ae = __builtin_amdgcn_mfma_f32_32x32x16_f16(a0, b0, ae, 0, 0, 0);
            ao = __builtin_amdgcn_mfma_f32_32x32x16_f16(a1, b1, ao, 0, 0, 0);
        }

        f16* st = Ostage[w];
        if (kind < 2) {
#pragma unroll
            for (int g = 0; g < 4; ++g) {
                f32x4 bb = *(const f32x4*)(bias + ct * 32 + 4 * hi + 8 * g);
                f16x4 pk;
#pragma unroll
                for (int e = 0; e < 4; ++e)
                    pk[e] = (f16)(ae[4 * g + e] + ao[4 * g + e] + bb[e] * bscale);
                *(f16x4*)(st + l31 * 32 + 4 * hi + 8 * g) = pk;
            }
            if (kind == 0) {
                f16* dst = qT + ((size_t)b * NPIX + i0 + half * 32) * CDIM + ct * 32;
#pragma unroll
                for (int d = 0; d < 2; ++d) {
                    int row = d * 16 + (lane >> 2);
                    int c8  = (lane & 3) * 8;
                    f16x8 v = *(const f16x8*)(st + row * 32 + c8);
                    *(f16x8*)(dst + (size_t)row * CDIM + c8) = v;
                }
            } else {
                const int j0 = i0 + half * 32;
                f16* dstb = kC + (size_t)b * CDIM * NPIX;
#pragma unroll
                for (int d = 0; d < 2; ++d) {
                    int row = d * 16 + (lane >> 2);   // j-local
                    int kl  = lane & 3;               // c-chunk-local
                    f16x8 v = *(const f16x8*)(st + row * 32 + kl * 8);
                    *(f16x8*)(dstb + ((size_t)(ct * 4 + kl) * NPIX + j0 + row) * 8) = v;
                }
            }
        } else {
#pragma unroll
            for (int g = 0; g < 4; ++g) {
                f32x4 bb = *(const f32x4*)(bias + ct * 32 + 4 * hi + 8 * g);
#pragma unroll
                for (int e = 0; e < 4; ++e) {
                    int c31 = 4 * hi + 8 * g + e;
                    st[c31 * 32 + l31] = (f16)(ae[4 * g + e] + ao[4 * g + e] + bb[e]);
                }
            }
            const int j0 = i0 + half * 32;
            f16* dstb = vW + (size_t)b * CDIM * NPIX + (size_t)(ct * 32) * NPIX + j0;
#pragma unroll
            for (int d = 0; d < 2; ++d) {
                int chunk = d * 64 + lane;
                int c31 = chunk >> 2, jch = chunk & 3;
                *(f16x8*)(dstb + (size_t)c31 * NPIX + jch * 8) =
                    *(const f16x8*)(st + chunk * 8);
            }
        }
    }
}

// ---------------- kernel 2: flash attention + residual ----------------
// 512 threads = 8 waves = 4 i-strips (pair pr=w&3) x 2 roles (chalf=w>>2); grid 256.
// NEW: split-O pipeline. Waves w / w+4 share an i-strip; each computes its own 32-j
// half's P (QK + softmax as before), EXCHANGES P via a 16KB LDS buffer, and
// accumulates only 4 c-tiles (chalf) over ALL 64 j -> acc[4] = 64 AGPR (was 128).
// Freed registers enable the V-lag QK(t) || PV(t-1) 1:1 interleave (R7 idea) WITHOUT
// the scratch spill that killed R7/R8. Two barriers/iter: staging-sync + P-exchange.
// K/V LDS layouts + swizzles R6-verified (0 conflicts). Epilogue: direct store
// (each wave owns distinct (c,i) outputs; no Obuf merge).
__global__ __launch_bounds__(512, 2)
void attn_kernel(const f16* __restrict__ qT, const f16* __restrict__ kC,
                 const f16* __restrict__ vW, const float* __restrict__ x,
                 float* __restrict__ out) {
    extern __shared__ unsigned char smem[];   // 148480 B: 2x64KB K/V dbuf + 16KB Pbuf + 1KB Lsm

    const int b     = blockIdx.x & 7;         // batch -> XCD pinning for K/V L2 reuse
    const int i0    = (blockIdx.x >> 3) * 128;
    const int t     = threadIdx.x;            // 0..511
    const int w     = t >> 6;
    const int lane  = t & 63;
    const int l31   = lane & 31;
    const int hi    = lane >> 5;
    const int pr    = w & 3;                  // i-strip (wave pair id)
    const int chalf = w >> 2;                 // 0: c-tiles 0-3 + j-half 0 ; 1: c-tiles 4-7 + j-half 1
    const int jh    = chalf * 32;             // own j-half (for QK)
    const int ig    = i0 + pr * 32 + l31;

    // Q B-frags in registers: B[k=c][n=i], n = l31, k-offset 8*hi
    f16x8 qf[16];
    {
        const f16* qp = qT + ((size_t)b * NPIX + ig) * CDIM + hi * 8;
#pragma unroll
        for (int ks = 0; ks < 16; ++ks) qf[ks] = *(const f16x8*)(qp + ks * 16);
    }

    // K read: row = kc*2+jhalf, pos = l31 (32 distinct, conflict-free, imm offsets)
    const int kbase = hi * 512 + chalf * 256 + l31 * 8;
    // V read (full 64 j now): slab kjg 0..3, chunk jc = 2*kjg+hi;
    // row = ct*8+(l31&7), pos = ((l31>>3)<<3)|(jc^(l31&7)) (32 distinct)
    int vp4o[4];
    {
        int vbase = 16384 + (l31 & 7) * 256 + ((l31 >> 3) << 6);
#pragma unroll
        for (int kjg = 0; kjg < 4; ++kjg)
            vp4o[kjg] = vbase + (((2 * kjg + hi) ^ (l31 & 7)) << 3);
    }

    f32x16 acc[4];                            // 4 c-tiles (chalf half), 64 AGPR
#pragma unroll
    for (int ct = 0; ct < 4; ++ct)
#pragma unroll
        for (int r = 0; r < 16; ++r) acc[ct][r] = 0.0f;
    float lrun = 0.0f;

    const f16* kb = kC + (size_t)b * CDIM * NPIX;   // chunk-major [kc][j][8]
    const f16* vb = vW + (size_t)b * CDIM * NPIX;
    f16* lds0 = (f16*)smem;
    f16* Pb   = lds0 + 65536 + pr * 2048;     // pair's P: [kjg(4)][lane(64)][8]
    const int wub = (t & ~63) * 8;            // wave-uniform staging base (f16 units)

    // prologue: stage K(0) into buffer 0 K-region
    {
#pragma unroll
        for (int rep = 0; rep < 4; ++rep) {
            int slot = t + rep * 512;
            int kc = slot >> 6, jhalf = (slot >> 5) & 1, pj = slot & 31;
            gl2lds16(kb + ((size_t)kc * NPIX + jhalf * 32 + pj) * 8,
                     lds0 + wub + rep * 4096);
        }
    }

    union Q4 { f16x4 h; unsigned int u[2]; };
    union B8 { f16x8 h; unsigned int u[4]; };

#pragma unroll 1
    for (int jt = 0; jt < 64; ++jt) {
        const int p = jt & 1;
        __syncthreads();   // bar1: K(jt)+V(jt-1) DMA done; P(jt-1) written; bufs safe

        // stage K(jt+1) -> kbuf[p^1]; V(jt) -> vbuf[p]
        {
            f16* kdst = lds0 + (p ^ 1) * 32768 + wub;
            f16* vdst = lds0 + p * 32768 + 16384 + wub;
            const int j0n = (jt + 1) * 64;
            const int j0v = jt * 64;
#pragma unroll
            for (int rep = 0; rep < 4; ++rep) {
                int slot = t + rep * 512;
                if (jt < 63) {
                    int kc = slot >> 6, jhalf = (slot >> 5) & 1, pj = slot & 31;
                    gl2lds16(kb + ((size_t)kc * NPIX + j0n + jhalf * 32 + pj) * 8,
                             kdst + rep * 4096);
                }
                int row = slot >> 5, pv = slot & 31;
                int vc = ((row >> 3) << 5) | (((pv >> 3) & 3) << 3) | (row & 7);
                int vjc = (pv & 7) ^ (row & 7);
                gl2lds16(vb + (size_t)vc * NPIX + j0v + vjc * 8,
                         vdst + rep * 4096);
            }
        }

        const f16* Lk = lds0 + p * 32768;                 // K(jt)
        const f16* Lv = lds0 + (p ^ 1) * 32768;           // V(jt-1) (vp4o adds +16384)

        // QK(jt) interleaved 1:1 with PV(jt-1): independent streams, acc chains
        // spaced 4 steps apart, s-chain stalls filled by PV MFMAs.
        f32x16 s;
#pragma unroll
        for (int r = 0; r < 16; ++r) s[r] = -SOFF;
        if (jt > 0) {
            f16x8 pf;
#pragma unroll
            for (int u = 0; u < 16; ++u) {
                const int kjg = u >> 2, ctl = u & 3;
                if ((u & 3) == 0) pf = *(const f16x8*)(Pb + kjg * 512 + lane * 8);
                s = __builtin_amdgcn_mfma_f32_32x32x16_f16(
                    *(const f16x8*)(Lk + kbase + u * 1024), qf[u], s, 0, 0, 0);
                acc[ctl] = __builtin_amdgcn_mfma_f32_32x32x16_f16(
                    *(const f16x8*)(Lv + vp4o[kjg] + (chalf * 4 + ctl) * 2048),
                    pf, acc[ctl], 0, 0, 0);
            }
        } else {
#pragma unroll
            for (int ks = 0; ks < 16; ++ks)
                s = __builtin_amdgcn_mfma_f32_32x32x16_f16(
                    *(const f16x8*)(Lk + kbase + ks * 1024), qf[ks], s, 0, 0, 0);
        }

        // fixed-offset softmax numerator; row-sum accumulates in-register
        Q4 ownq[4];
        float rtot = 0.0f;
#pragma unroll
        for (int g = 0; g < 4; ++g) {
            float p0 = __builtin_amdgcn_exp2f(s[4 * g + 0]);
            float p1 = __builtin_amdgcn_exp2f(s[4 * g + 1]);
            float p2 = __builtin_amdgcn_exp2f(s[4 * g + 2]);
            float p3 = __builtin_amdgcn_exp2f(s[4 * g + 3]);
            rtot += (p0 + p1) + (p2 + p3);
            ownq[g].h[0] = (f16)p0; ownq[g].h[1] = (f16)p1;
            ownq[g].h[2] = (f16)p2; ownq[g].h[3] = (f16)p3;
        }
        lrun += rtot;

        // P: C-layout -> B-layout via lane^32 quad exchange
        f16x8 pb[2];
#pragma unroll
        for (int kj = 0; kj < 2; ++kj) {
            int sidx = 2 * kj + 1 - hi;
            int oidx = 2 * kj + hi;
            unsigned int s0 = ownq[sidx].u[0], s1 = ownq[sidx].u[1];
            unsigned int r0 = (unsigned int)__shfl_xor((int)s0, 32);
            unsigned int r1 = (unsigned int)__shfl_xor((int)s1, 32);
            B8 bb;
            bb.u[0] = hi ? r0 : ownq[oidx].u[0];
            bb.u[1] = hi ? r1 : ownq[oidx].u[1];
            bb.u[2] = hi ? ownq[oidx].u[0] : r0;
            bb.u[3] = hi ? ownq[oidx].u[1] : r1;
            pb[kj] = bb.h;
        }

        __syncthreads();   // bar2: all PV reads of P(jt-1) complete -> safe to overwrite
        // publish P(jt): own global slabs kjg = chalf*2 + {0,1}
        *(f16x8*)(Pb + (chalf * 2 + 0) * 512 + lane * 8) = pb[0];
        *(f16x8*)(Pb + (chalf * 2 + 1) * 512 + lane * 8) = pb[1];
    }

    // drain: PV(63); V(63) in buffer1 V-region, P(63) in Pbuf
    __syncthreads();
    {
        const f16* Lv = lds0 + 32768;   // p=1 buffer (vp4o adds +16384)
#pragma unroll
        for (int kjg = 0; kjg < 4; ++kjg) {
            f16x8 pf = *(const f16x8*)(Pb + kjg * 512 + lane * 8);
#pragma unroll
            for (int ctl = 0; ctl < 4; ++ctl)
                acc[ctl] = __builtin_amdgcn_mfma_f32_32x32x16_f16(
                    *(const f16x8*)(Lv + vp4o[kjg] + (chalf * 4 + ctl) * 2048),
                    pf, acc[ctl], 0, 0, 0);
        }
    }

    // ---- epilogue: merge pair l-sums, direct coalesced residual store ----
    float lsum = lrun + __shfl_xor(lrun, 32);       // own 32-j half total per i-row
    float* Lsm = (float*)(smem + 147456);           // 256 floats
    if (hi == 0) Lsm[w * 32 + l31] = lsum;
    __syncthreads();
    const float ltot = lsum + Lsm[(w ^ 4) * 32 + l31];
    const float invl = 1.0f / ltot;
    const float* xb = x + (size_t)b * CDIM * NPIX;
    float* og = out + (size_t)b * CDIM * NPIX;
#pragma unroll
    for (int ctl = 0; ctl < 4; ++ctl)
#pragma unroll
        for (int r = 0; r < 16; ++r) {
            int c = (chalf * 4 + ctl) * 32 + (r & 3) + 8 * (r >> 2) + 4 * hi;
            size_t off = (size_t)c * NPIX + ig;
            og[off] = acc[ctl][r] * invl + xb[off];
        }
}

extern "C" void kernel_launch(void* const* d_in, const int* in_sizes, int n_in,
                              void* d_out, int out_size, void* d_ws, size_t ws_size,
                              hipStream_t stream) {
    const float* x    = (const float*)d_in[0];
    const float* attr = (const float*)d_in[1];
    const float* Wq   = (const float*)d_in[2];
    const float* bq   = (const float*)d_in[3];
    const float* Wk   = (const float*)d_in[4];
    const float* bk   = (const float*)d_in[5];
    const float* Wv   = (const float*)d_in[6];
    const float* bv   = (const float*)d_in[7];
    float* out = (float*)d_out;

    // workspace layout (~48.4 MB)
    char* ws = (char*)d_ws;
    const size_t qkv_bytes = (size_t)8 * NPIX * CDIM * sizeof(f16);  // 16 MB each
    f16* qT   = (f16*)ws;
    f16* kC   = (f16*)(ws + qkv_bytes);
    f16* vW   = (f16*)(ws + 2 * qkv_bytes);
    f16* WqF  = (f16*)(ws + 3 * qkv_bytes);
    f16* WkF  = WqF + 65536;
    f16* WvF  = WkF + 65536;

    (void)hipFuncSetAttribute((const void*)attn_kernel,
                              hipFuncAttributeMaxDynamicSharedMemorySize, 148480);

    convert_w_kernel<<<96, 256, 0, stream>>>(Wq, Wk, Wv, WqF, WkF, WvF);
    proj_kernel<<<512, 256, 0, stream>>>(x, attr, WqF, bq, WkF, bk, WvF, bv, qT, kC, vW);
    attn_kernel<<<256, 512, 148480, stream>>>(qT, kC, vW, x, out);
}